// Round 2
// baseline (116.880 us; speedup 1.0000x reference)
//
#include <hip/hip_runtime.h>

typedef short short8 __attribute__((ext_vector_type(8)));
typedef float floatx4 __attribute__((ext_vector_type(4)));
typedef float floatx16 __attribute__((ext_vector_type(16)));
typedef unsigned int u32;

#define NEG_SLOPE 0.2f

// pack {bf16_rtne(b), bf16_rtne(a)} into one u32 (a in low half)
__device__ __forceinline__ u32 pk_rtne(float a, float b) {
    u32 ua = __float_as_uint(a); ua += 0x7fffu + ((ua >> 16) & 1u);
    u32 ub = __float_as_uint(b); ub += 0x7fffu + ((ub >> 16) & 1u);
    return __builtin_amdgcn_perm(ub, ua, 0x07060302);
}
// pack {trunc16(b), trunc16(a)} — 1 inst per pair
__device__ __forceinline__ u32 pk_trunc(float a, float b) {
    return __builtin_amdgcn_perm(__float_as_uint(b), __float_as_uint(a), 0x07060302);
}
__device__ __forceinline__ void gl_lds16(const void* g, void* l) {
    __builtin_amdgcn_global_load_lds((__attribute__((address_space(1))) u32*)(void*)g,
                                     (__attribute__((address_space(3))) u32*)l, 16, 0, 0);
}

// ---------------------------------------------------------------------------
// Kernel 1: Wh = h @ W^T (single-pass bf16 MFMA, 16x16x32), barrier-free main
// loop. Scores s1/s2 computed EXACTLY in fp32 via s = h · (W^T a)  (v-GEMV
// folded into the W staging pass). Outputs:
//  - WhF: Wh^T as pre-swizzled 32x32x16 MFMA *B*-fragments
//    [b4h][jt16(64)][nt32(2)][lane(64)][8 bf16]
//    with k-slot permutation pi(g,jj) = (jj&3) + 4*g + 8*(jj>>2)
//    (chosen so k_wh's 16x16 C-quads store with plain uint2 writes)
//  - E1F1[b4h,i] = (exp(s1), exp(0.2*s1)); E2F2[b4h,j] = m_j*(exp(s2), exp(0.2*s2))
// Grid 1024 = 256 mtiles x 4 heads; h-tile sharers stride 256 -> same XCD.
// ---------------------------------------------------------------------------
__global__ __launch_bounds__(256, 4) void k_wh(
    const float* __restrict__ hin, const int* __restrict__ mask,
    const float* __restrict__ W, const float* __restrict__ a,
    unsigned short* __restrict__ WhF, float2* __restrict__ E1F1,
    float2* __restrict__ E2F2)
{
    __shared__ unsigned short sBF[8 * 4 * 64 * 8];  // W as 16x16x32 B-frags, 32 KB
    __shared__ float sV1[256], sV2[256];

    const int t = threadIdx.x;
    const int bi = blockIdx.x;
    const int mtile = bi & 255, hh = bi >> 8;
    const int m0g = mtile * 64;             // global row = b*1024 + i0
    const int b = m0g >> 10, i0 = m0g & 1023;
    const int b4h = b * 4 + hh;
    const int wid = t >> 6, lane = t & 63;
    const int l15 = lane & 15, q = lane >> 4;

    sV1[t] = 0.f;
    sV2[t] = 0.f;
    __syncthreads();

    // ---- stage W (this head) as B-frags + v1/v2 partial GEMV ----
    float vp1[8] = {0, 0, 0, 0, 0, 0, 0, 0};
    float vp2[8] = {0, 0, 0, 0, 0, 0, 0, 0};
    {
        const int c = t & 31;               // k-chunk of 8 floats
        const int rb = t >> 5;
#pragma unroll
        for (int i = 0; i < 8; ++i) {
            int row = i * 8 + rb;           // d within head
            const float* gp = &W[((size_t)(hh * 64 + row)) * 256 + c * 8];
            float4 w0 = *(const float4*)gp;
            float4 w1 = *(const float4*)(gp + 4);
            float a1r = a[row], a2r = a[64 + row];
            vp1[0] += a1r * w0.x; vp1[1] += a1r * w0.y; vp1[2] += a1r * w0.z; vp1[3] += a1r * w0.w;
            vp1[4] += a1r * w1.x; vp1[5] += a1r * w1.y; vp1[6] += a1r * w1.z; vp1[7] += a1r * w1.w;
            vp2[0] += a2r * w0.x; vp2[1] += a2r * w0.y; vp2[2] += a2r * w0.z; vp2[3] += a2r * w0.w;
            vp2[4] += a2r * w1.x; vp2[5] += a2r * w1.y; vp2[6] += a2r * w1.z; vp2[7] += a2r * w1.w;
            uint4 pv;
            pv.x = pk_rtne(w0.x, w0.y); pv.y = pk_rtne(w0.z, w0.w);
            pv.z = pk_rtne(w1.x, w1.y); pv.w = pk_rtne(w1.z, w1.w);
            int kt = c >> 2, qq = c & 3, nt = row >> 4, r15 = row & 15;
            int idx16 = (kt * 4 + nt) * 64 + qq * 16 + r15;
            *(uint4*)&sBF[(idx16 ^ kt) * 8] = pv;   // XOR swizzle: 32-way -> 4-way
        }
    }
#pragma unroll
    for (int j = 0; j < 8; ++j) {
        vp1[j] += __shfl_xor(vp1[j], 32, 64);
        vp2[j] += __shfl_xor(vp2[j], 32, 64);
    }
    if (lane < 32) {
        const int c = t & 31;
#pragma unroll
        for (int j = 0; j < 8; ++j) {
            atomicAdd(&sV1[c * 8 + j], vp1[j]);
            atomicAdd(&sV2[c * 8 + j], vp2[j]);
        }
    }
    __syncthreads();

    // ---- main loop: A-frags direct from global, no barriers ----
    floatx4 acc[4];
#pragma unroll
    for (int nt = 0; nt < 4; ++nt) {
        floatx4 z = {0.f, 0.f, 0.f, 0.f};
        acc[nt] = z;
    }
    float s1a = 0.f, s2a = 0.f;
    const float* hrow = &hin[((size_t)(m0g + wid * 16 + l15)) * 256 + q * 8];
#pragma unroll
    for (int kt = 0; kt < 8; ++kt) {
        float4 h0 = *(const float4*)(hrow + kt * 32);
        float4 h1 = *(const float4*)(hrow + kt * 32 + 4);
        float4 v1a = *(const float4*)&sV1[kt * 32 + q * 8];
        float4 v1b = *(const float4*)&sV1[kt * 32 + q * 8 + 4];
        float4 v2a = *(const float4*)&sV2[kt * 32 + q * 8];
        float4 v2b = *(const float4*)&sV2[kt * 32 + q * 8 + 4];
        s1a += h0.x * v1a.x + h0.y * v1a.y + h0.z * v1a.z + h0.w * v1a.w
             + h1.x * v1b.x + h1.y * v1b.y + h1.z * v1b.z + h1.w * v1b.w;
        s2a += h0.x * v2a.x + h0.y * v2a.y + h0.z * v2a.z + h0.w * v2a.w
             + h1.x * v2b.x + h1.y * v2b.y + h1.z * v2b.z + h1.w * v2b.w;
        union { short8 s; uint4 u; } af;
        af.u.x = pk_rtne(h0.x, h0.y); af.u.y = pk_rtne(h0.z, h0.w);
        af.u.z = pk_rtne(h1.x, h1.y); af.u.w = pk_rtne(h1.z, h1.w);
#pragma unroll
        for (int nt = 0; nt < 4; ++nt) {
            int idx16 = (kt * 4 + nt) * 64 + lane;
            short8 bf = *(const short8*)&sBF[(idx16 ^ kt) * 8];
            acc[nt] = __builtin_amdgcn_mfma_f32_16x16x32_bf16(af.s, bf, acc[nt], 0, 0, 0);
        }
    }

    // ---- epilogue: store WhF as 32x32x16 B-frags under pi ----
    // source C (16x16): lane(l15,q) holds rows q*4+r, col nt*16+l15.
    // row&15 = q*4+r -> (g = q&1, jj = 4*(q>>1)+r)  [pi identity: 4q = 4(q&1)+8(q>>1)]
    const int jt16 = (i0 >> 4) + wid;       // 16-j tile index within head
    const int g = q & 1, jb = (q >> 1) * 4;
#pragma unroll
    for (int nt = 0; nt < 4; ++nt) {
        int nt32 = nt >> 1;
        int l31 = (nt & 1) * 16 + l15;
        uint2 pv;
        pv.x = pk_rtne(acc[nt][0], acc[nt][1]);
        pv.y = pk_rtne(acc[nt][2], acc[nt][3]);
        size_t idx = ((((size_t)b4h * 64 + jt16) * 2 + nt32) * 64 + (g * 32 + l31)) * 8 + jb;
        *(uint2*)&WhF[idx] = pv;
    }

    // ---- scores: fold q (xor 16,32), write E/F ----
    s1a += __shfl_xor(s1a, 16, 64); s1a += __shfl_xor(s1a, 32, 64);
    s2a += __shfl_xor(s2a, 16, 64); s2a += __shfl_xor(s2a, 32, 64);
    if (lane < 16) {
        int i = i0 + wid * 16 + lane;
        E1F1[(size_t)b4h * 1024 + i] = make_float2(__expf(s1a), __expf(NEG_SLOPE * s1a));
        int mj = mask[b * 1024 + i];
        E2F2[(size_t)b4h * 1024 + i] =
            make_float2(mj ? __expf(s2a) : 0.f, mj ? __expf(NEG_SLOPE * s2a) : 0.f);
    }
}

// ---------------------------------------------------------------------------
// Kernel 2: out[i,:] = (sum_j w_ij Wh[j,:]) / (sum_j w_ij),
// w_ij = max(E1_i*E2_j, F1_i*F2_j). 32x32x16 MFMA (32-row waves -> halved LDS
// traffic); denominator via ones-column MFMA (accL), exactly consistent with
// the truncated-bf16 P fed to the numerator. 512 blocks = (b4h, 128 rows);
// sharers of b4h at stride 64 -> same XCD -> WhF slab L2-resident.
//
// R1 change: E2F2 operand pairs are read DIRECTLY FROM GLOBAL (8 KB slab,
// L1-resident; each chunk's 16 float2 = exactly one 128 B line, broadcast
// across each g-half) with a 1-chunk software prefetch. This removes 4 of 6
// ds_read_b128 per (wave,chunk) — the LDS pipe was the bottleneck — and the
// sEF staging entirely.
// ---------------------------------------------------------------------------
__global__ __launch_bounds__(256, 2) void k_attn(
    const int* __restrict__ mask,
    const unsigned short* __restrict__ WhF,
    const float2* __restrict__ E1F1, const float2* __restrict__ E2F2,
    float* __restrict__ out)
{
    __shared__ unsigned short sB[2][8192];   // [jtile(8)][nt(2)][lane][8], 16 KB/buf

    const int t = threadIdx.x;
    const int bi = blockIdx.x;
    const int b4h = bi & 63, ib = bi >> 6;
    const int b = b4h >> 2, hh = b4h & 3;
    const int i0 = ib * 128;
    const int wid = t >> 6, lane = t & 63;
    const int l31 = lane & 31, g = lane >> 5;
    const int iw = i0 + wid * 32;

    float2 e1 = E1F1[(size_t)b4h * 1024 + iw + l31];   // A-operand row m = l31
    const float E1 = e1.x, F1 = e1.y;

    floatx16 acc0, acc1, accL;
#pragma unroll
    for (int r = 0; r < 16; ++r) { acc0[r] = 0.f; acc1[r] = 0.f; accL[r] = 0.f; }
    const short ob = (short)0x3F80;          // bf16 1.0
    const short8 ones = {ob, ob, ob, ob, ob, ob, ob, ob};

    const char* gbase = (const char*)WhF + (size_t)b4h * 131072;
    const float2* EFb = E2F2 + (size_t)b4h * 1024;

    // E/F pair loads, straight from global (one 128B line per chunk):
    // chunk c covers pairs [c*16 .. c*16+15]; this lane (g-half) needs
    // pairs [c*16+g*4 .. +3] and [c*16+8+g*4 .. +3]  (pi slot map).
    float4 nA0, nA1, nB0, nB1;
    {
        const float4* p = (const float4*)EFb + (g << 1);
        nA0 = p[0]; nA1 = p[1]; nB0 = p[4]; nB1 = p[5];
    }

    // prefetch jt=0 Wh fragments
    {
#pragma unroll
        for (int i = 0; i < 4; ++i)
            gl_lds16(gbase + wid * 4096 + i * 1024 + lane * 16,
                     (char*)&sB[0][0] + wid * 4096 + i * 1024);
    }

    for (int jt = 0; jt < 8; ++jt) {
        const int buf = jt & 1;
        __syncthreads();
        if (jt < 7) {
            const char* gp = gbase + (size_t)(jt + 1) * 16384;
#pragma unroll
            for (int i = 0; i < 4; ++i)
                gl_lds16(gp + wid * 4096 + i * 1024 + lane * 16,
                         (char*)&sB[buf ^ 1][0] + wid * 4096 + i * 1024);
        }
#pragma unroll
        for (int tl = 0; tl < 8; ++tl) {
            // consume prefetched E/F pairs for this chunk, prefetch next
            const float4 eA0 = nA0, eA1 = nA1, eB0 = nB0, eB1 = nB1;
            {
                const int cn = (jt * 8 + tl + 1) & 63;
                const float4* p = (const float4*)EFb + (cn << 3) + (g << 1);
                nA0 = p[0]; nA1 = p[1]; nB0 = p[4]; nB1 = p[5];
            }
            // slots jj 0..7 <-> j = tl*16 + {4g+0..3, 8+4g+0..3}   (pi map)
            float w0 = fmaxf(E1 * eA0.x, F1 * eA0.y);
            float w1 = fmaxf(E1 * eA0.z, F1 * eA0.w);
            float w2 = fmaxf(E1 * eA1.x, F1 * eA1.y);
            float w3 = fmaxf(E1 * eA1.z, F1 * eA1.w);
            float w4 = fmaxf(E1 * eB0.x, F1 * eB0.y);
            float w5 = fmaxf(E1 * eB0.z, F1 * eB0.w);
            float w6 = fmaxf(E1 * eB1.x, F1 * eB1.y);
            float w7 = fmaxf(E1 * eB1.z, F1 * eB1.w);
            union { short8 s; u32 u[4]; } af;
            af.u[0] = pk_trunc(w0, w1);
            af.u[1] = pk_trunc(w2, w3);
            af.u[2] = pk_trunc(w4, w5);
            af.u[3] = pk_trunc(w6, w7);
            short8 bf0 = *(const short8*)&sB[buf][((tl * 2 + 0) * 64 + lane) * 8];
            short8 bf1 = *(const short8*)&sB[buf][((tl * 2 + 1) * 64 + lane) * 8];
            acc0 = __builtin_amdgcn_mfma_f32_32x32x16_bf16(af.s, bf0, acc0, 0, 0, 0);
            acc1 = __builtin_amdgcn_mfma_f32_32x32x16_bf16(af.s, bf1, acc1, 0, 0, 0);
            accL = __builtin_amdgcn_mfma_f32_32x32x16_bf16(af.s, ones, accL, 0, 0, 0);
        }
    }

    // epilogue: C/D 32x32 layout: col = l31, row = (r&3) + 8*(r>>2) + 4*g
#pragma unroll
    for (int r = 0; r < 16; ++r) {
        int row = (r & 3) + 8 * (r >> 2) + 4 * g;
        int i = iw + row;
        float l = accL[r];
        int mi = mask[b * 1024 + i];
        float inv = (mi && l > 0.f) ? 1.0f / l : 0.f;
        size_t o = ((size_t)(b * 1024 + i)) * 256 + hh * 64;
        out[o + l31] = acc0[r] * inv;
        out[o + 32 + l31] = acc1[r] * inv;
    }
}

extern "C" void kernel_launch(void* const* d_in, const int* in_sizes, int n_in,
                              void* d_out, int out_size, void* d_ws, size_t ws_size,
                              hipStream_t stream) {
    const float* h = (const float*)d_in[0];
    const int* mask = (const int*)d_in[1];
    const float* W = (const float*)d_in[2];
    const float* a = (const float*)d_in[3];
    float* out = (float*)d_out;

    // ws: WhF bf16 frags [64 b4h][64 jt16][2 nt][64 lane][8] = 8 MiB; then E1F1, E2F2
    unsigned short* WhF = (unsigned short*)d_ws;
    float2* E1F1 = (float2*)((char*)d_ws + (size_t)64 * 64 * 2 * 64 * 8 * 2);
    float2* E2F2 = E1F1 + 64 * 1024;

    hipLaunchKernelGGL(k_wh, dim3(1024), dim3(256), 0, stream, h, mask, W, a, WhF, E1F1, E2F2);
    hipLaunchKernelGGL(k_attn, dim3(512), dim3(256), 0, stream, mask, WhF, E1F1, E2F2, out);
}

// Round 3
// 111.570 us; speedup vs baseline: 1.0476x; 1.0476x over previous
//
#include <hip/hip_runtime.h>

typedef short short8 __attribute__((ext_vector_type(8)));
typedef float floatx4 __attribute__((ext_vector_type(4)));
typedef float floatx16 __attribute__((ext_vector_type(16)));
typedef unsigned int u32;

#define NEG_SLOPE 0.2f

// pack {bf16_rtne(b), bf16_rtne(a)} into one u32 (a in low half)
__device__ __forceinline__ u32 pk_rtne(float a, float b) {
    u32 ua = __float_as_uint(a); ua += 0x7fffu + ((ua >> 16) & 1u);
    u32 ub = __float_as_uint(b); ub += 0x7fffu + ((ub >> 16) & 1u);
    return __builtin_amdgcn_perm(ub, ua, 0x07060302);
}
// pack {trunc16(b), trunc16(a)} — 1 inst per pair
__device__ __forceinline__ u32 pk_trunc(float a, float b) {
    return __builtin_amdgcn_perm(__float_as_uint(b), __float_as_uint(a), 0x07060302);
}
__device__ __forceinline__ void gl_lds16(const void* g, void* l) {
    __builtin_amdgcn_global_load_lds((__attribute__((address_space(1))) u32*)(void*)g,
                                     (__attribute__((address_space(3))) u32*)l, 16, 0, 0);
}

// ---------------------------------------------------------------------------
// Kernel 1: Wh = h @ W^T (single-pass bf16 MFMA, 16x16x32), barrier-free main
// loop. Scores s1/s2 computed EXACTLY in fp32 via s = h · (W^T a)  (v-GEMV
// folded into the W staging pass). Outputs:
//  - WhF: Wh^T as pre-swizzled 32x32x16 MFMA *B*-fragments
//    [b4h][jt16(64)][nt32(2)][lane(64)][8 bf16]
//    with k-slot permutation pi(g,jj) = (jj&3) + 4*g + 8*(jj>>2)
//    (chosen so k_wh's 16x16 C-quads store with plain uint2 writes)
//  - E1F1[b4h,i] = (exp(s1), exp(0.2*s1)); E2F2[b4h,j] = m_j*(exp(s2), exp(0.2*s2))
// Grid 1024 = 256 mtiles x 4 heads; h-tile sharers stride 256 -> same XCD.
// ---------------------------------------------------------------------------
__global__ __launch_bounds__(256, 4) void k_wh(
    const float* __restrict__ hin, const int* __restrict__ mask,
    const float* __restrict__ W, const float* __restrict__ a,
    unsigned short* __restrict__ WhF, float2* __restrict__ E1F1,
    float2* __restrict__ E2F2)
{
    __shared__ unsigned short sBF[8 * 4 * 64 * 8];  // W as 16x16x32 B-frags, 32 KB
    __shared__ float sV1[256], sV2[256];

    const int t = threadIdx.x;
    const int bi = blockIdx.x;
    const int mtile = bi & 255, hh = bi >> 8;
    const int m0g = mtile * 64;             // global row = b*1024 + i0
    const int b = m0g >> 10, i0 = m0g & 1023;
    const int b4h = b * 4 + hh;
    const int wid = t >> 6, lane = t & 63;
    const int l15 = lane & 15, q = lane >> 4;

    sV1[t] = 0.f;
    sV2[t] = 0.f;
    __syncthreads();

    // ---- stage W (this head) as B-frags + v1/v2 partial GEMV ----
    float vp1[8] = {0, 0, 0, 0, 0, 0, 0, 0};
    float vp2[8] = {0, 0, 0, 0, 0, 0, 0, 0};
    {
        const int c = t & 31;               // k-chunk of 8 floats
        const int rb = t >> 5;
#pragma unroll
        for (int i = 0; i < 8; ++i) {
            int row = i * 8 + rb;           // d within head
            const float* gp = &W[((size_t)(hh * 64 + row)) * 256 + c * 8];
            float4 w0 = *(const float4*)gp;
            float4 w1 = *(const float4*)(gp + 4);
            float a1r = a[row], a2r = a[64 + row];
            vp1[0] += a1r * w0.x; vp1[1] += a1r * w0.y; vp1[2] += a1r * w0.z; vp1[3] += a1r * w0.w;
            vp1[4] += a1r * w1.x; vp1[5] += a1r * w1.y; vp1[6] += a1r * w1.z; vp1[7] += a1r * w1.w;
            vp2[0] += a2r * w0.x; vp2[1] += a2r * w0.y; vp2[2] += a2r * w0.z; vp2[3] += a2r * w0.w;
            vp2[4] += a2r * w1.x; vp2[5] += a2r * w1.y; vp2[6] += a2r * w1.z; vp2[7] += a2r * w1.w;
            uint4 pv;
            pv.x = pk_rtne(w0.x, w0.y); pv.y = pk_rtne(w0.z, w0.w);
            pv.z = pk_rtne(w1.x, w1.y); pv.w = pk_rtne(w1.z, w1.w);
            int kt = c >> 2, qq = c & 3, nt = row >> 4, r15 = row & 15;
            int idx16 = (kt * 4 + nt) * 64 + qq * 16 + r15;
            *(uint4*)&sBF[(idx16 ^ kt) * 8] = pv;   // XOR swizzle: 32-way -> 4-way
        }
    }
#pragma unroll
    for (int j = 0; j < 8; ++j) {
        vp1[j] += __shfl_xor(vp1[j], 32, 64);
        vp2[j] += __shfl_xor(vp2[j], 32, 64);
    }
    if (lane < 32) {
        const int c = t & 31;
#pragma unroll
        for (int j = 0; j < 8; ++j) {
            atomicAdd(&sV1[c * 8 + j], vp1[j]);
            atomicAdd(&sV2[c * 8 + j], vp2[j]);
        }
    }
    __syncthreads();

    // ---- main loop: A-frags direct from global, no barriers ----
    floatx4 acc[4];
#pragma unroll
    for (int nt = 0; nt < 4; ++nt) {
        floatx4 z = {0.f, 0.f, 0.f, 0.f};
        acc[nt] = z;
    }
    float s1a = 0.f, s2a = 0.f;
    const float* hrow = &hin[((size_t)(m0g + wid * 16 + l15)) * 256 + q * 8];
#pragma unroll
    for (int kt = 0; kt < 8; ++kt) {
        float4 h0 = *(const float4*)(hrow + kt * 32);
        float4 h1 = *(const float4*)(hrow + kt * 32 + 4);
        float4 v1a = *(const float4*)&sV1[kt * 32 + q * 8];
        float4 v1b = *(const float4*)&sV1[kt * 32 + q * 8 + 4];
        float4 v2a = *(const float4*)&sV2[kt * 32 + q * 8];
        float4 v2b = *(const float4*)&sV2[kt * 32 + q * 8 + 4];
        s1a += h0.x * v1a.x + h0.y * v1a.y + h0.z * v1a.z + h0.w * v1a.w
             + h1.x * v1b.x + h1.y * v1b.y + h1.z * v1b.z + h1.w * v1b.w;
        s2a += h0.x * v2a.x + h0.y * v2a.y + h0.z * v2a.z + h0.w * v2a.w
             + h1.x * v2b.x + h1.y * v2b.y + h1.z * v2b.z + h1.w * v2b.w;
        union { short8 s; uint4 u; } af;
        af.u.x = pk_rtne(h0.x, h0.y); af.u.y = pk_rtne(h0.z, h0.w);
        af.u.z = pk_rtne(h1.x, h1.y); af.u.w = pk_rtne(h1.z, h1.w);
#pragma unroll
        for (int nt = 0; nt < 4; ++nt) {
            int idx16 = (kt * 4 + nt) * 64 + lane;
            short8 bf = *(const short8*)&sBF[(idx16 ^ kt) * 8];
            acc[nt] = __builtin_amdgcn_mfma_f32_16x16x32_bf16(af.s, bf, acc[nt], 0, 0, 0);
        }
    }

    // ---- epilogue: store WhF as 32x32x16 B-frags under pi ----
    // source C (16x16): lane(l15,q) holds rows q*4+r, col nt*16+l15.
    // row&15 = q*4+r -> (g = q&1, jj = 4*(q>>1)+r)  [pi identity: 4q = 4(q&1)+8(q>>1)]
    const int jt16 = (i0 >> 4) + wid;       // 16-j tile index within head
    const int g = q & 1, jb = (q >> 1) * 4;
#pragma unroll
    for (int nt = 0; nt < 4; ++nt) {
        int nt32 = nt >> 1;
        int l31 = (nt & 1) * 16 + l15;
        uint2 pv;
        pv.x = pk_rtne(acc[nt][0], acc[nt][1]);
        pv.y = pk_rtne(acc[nt][2], acc[nt][3]);
        size_t idx = ((((size_t)b4h * 64 + jt16) * 2 + nt32) * 64 + (g * 32 + l31)) * 8 + jb;
        *(uint2*)&WhF[idx] = pv;
    }

    // ---- scores: fold q (xor 16,32), write E/F ----
    s1a += __shfl_xor(s1a, 16, 64); s1a += __shfl_xor(s1a, 32, 64);
    s2a += __shfl_xor(s2a, 16, 64); s2a += __shfl_xor(s2a, 32, 64);
    if (lane < 16) {
        int i = i0 + wid * 16 + lane;
        E1F1[(size_t)b4h * 1024 + i] = make_float2(__expf(s1a), __expf(NEG_SLOPE * s1a));
        int mj = mask[b * 1024 + i];
        E2F2[(size_t)b4h * 1024 + i] =
            make_float2(mj ? __expf(s2a) : 0.f, mj ? __expf(NEG_SLOPE * s2a) : 0.f);
    }
}

// ---------------------------------------------------------------------------
// Kernel 2: out[i,:] = (sum_j w_ij Wh[j,:]) / (sum_j w_ij),
// w_ij = max(E1_i*E2_j, F1_i*F2_j). 32x32x16 MFMA; denominator via ones-column
// MFMA (accL), exactly consistent with the truncated-bf16 P. 512 blocks =
// (b4h, 128 rows); sharers of b4h at stride 64 -> same XCD.
//
// R2 structure: NO Wh LDS staging. B-fragments stream directly from global
// (128 KB slab, L2-resident on its XCD; both co-resident blocks of a CU read
// the same slab) with a 1-chunk register prefetch — vmcnt carries only these
// counted pipelined loads (the R1 regression was E/F global loads draining
// the global_load_lds prefetch queue via shared vmcnt). E/F pairs live in an
// 8 KB LDS slab staged ONCE; 4 broadcast ds_read_b128 per chunk. Main loop
// has zero barriers.
// ---------------------------------------------------------------------------
__global__ __launch_bounds__(256, 2) void k_attn(
    const int* __restrict__ mask,
    const unsigned short* __restrict__ WhF,
    const float2* __restrict__ E1F1, const float2* __restrict__ E2F2,
    float* __restrict__ out)
{
    __shared__ float2 sEF[1024];             // 8 KB, staged once

    const int t = threadIdx.x;
    const int bi = blockIdx.x;
    const int b4h = bi & 63, ib = bi >> 6;
    const int b = b4h >> 2, hh = b4h & 3;
    const int i0 = ib * 128;
    const int wid = t >> 6, lane = t & 63;
    const int l31 = lane & 31, g = lane >> 5;
    const int iw = i0 + wid * 32;

    // stage the whole E2F2 slab (8 KB) once
    {
        const char* src = (const char*)(E2F2 + (size_t)b4h * 1024);
        gl_lds16(src + t * 16, (char*)sEF + t * 16);
        gl_lds16(src + 4096 + t * 16, (char*)sEF + 4096 + t * 16);
    }

    float2 e1 = E1F1[(size_t)b4h * 1024 + iw + l31];   // A-operand row m = l31
    const float E1 = e1.x, F1 = e1.y;

    floatx16 acc0, acc1, accL;
#pragma unroll
    for (int r = 0; r < 16; ++r) { acc0[r] = 0.f; acc1[r] = 0.f; accL[r] = 0.f; }
    const short ob = (short)0x3F80;          // bf16 1.0
    const short8 ones = {ob, ob, ob, ob, ob, ob, ob, ob};

    // per-lane base into the B-fragment slab: chunk c at + c*2048 (+1024 for nt=1)
    const char* gbase = (const char*)WhF + (size_t)b4h * 131072 + (size_t)lane * 16;

    __syncthreads();                         // sEF ready (barrier drains vmcnt)

    // register prefetch: chunk 0 B-frags (global) + chunk 0 E/F pairs (LDS)
    short8 nb0 = *(const short8*)(gbase);
    short8 nb1 = *(const short8*)(gbase + 1024);
    float4 nA0, nA1, nB0, nB1;
    {
        const float4* pA = (const float4*)&sEF[g * 4];
        const float4* pB = (const float4*)&sEF[8 + g * 4];
        nA0 = pA[0]; nA1 = pA[1]; nB0 = pB[0]; nB1 = pB[1];
    }

#pragma unroll 8
    for (int c = 0; c < 64; ++c) {
        const short8 bf0 = nb0, bf1 = nb1;
        const float4 eA0 = nA0, eA1 = nA1, eB0 = nB0, eB1 = nB1;
        {   // prefetch chunk c+1 (wraps to 0 on last iter; always in-bounds)
            const int cn = (c + 1) & 63;
            nb0 = *(const short8*)(gbase + (size_t)cn * 2048);
            nb1 = *(const short8*)(gbase + (size_t)cn * 2048 + 1024);
            const float4* pA = (const float4*)&sEF[cn * 16 + g * 4];
            const float4* pB = (const float4*)&sEF[cn * 16 + 8 + g * 4];
            nA0 = pA[0]; nA1 = pA[1]; nB0 = pB[0]; nB1 = pB[1];
        }
        // slots jj 0..7 <-> j = c*16 + {4g+0..3, 8+4g+0..3}   (pi map)
        float w0 = fmaxf(E1 * eA0.x, F1 * eA0.y);
        float w1 = fmaxf(E1 * eA0.z, F1 * eA0.w);
        float w2 = fmaxf(E1 * eA1.x, F1 * eA1.y);
        float w3 = fmaxf(E1 * eA1.z, F1 * eA1.w);
        float w4 = fmaxf(E1 * eB0.x, F1 * eB0.y);
        float w5 = fmaxf(E1 * eB0.z, F1 * eB0.w);
        float w6 = fmaxf(E1 * eB1.x, F1 * eB1.y);
        float w7 = fmaxf(E1 * eB1.z, F1 * eB1.w);
        union { short8 s; u32 u[4]; } af;
        af.u[0] = pk_trunc(w0, w1);
        af.u[1] = pk_trunc(w2, w3);
        af.u[2] = pk_trunc(w4, w5);
        af.u[3] = pk_trunc(w6, w7);
        acc0 = __builtin_amdgcn_mfma_f32_32x32x16_bf16(af.s, bf0, acc0, 0, 0, 0);
        acc1 = __builtin_amdgcn_mfma_f32_32x32x16_bf16(af.s, bf1, acc1, 0, 0, 0);
        accL = __builtin_amdgcn_mfma_f32_32x32x16_bf16(af.s, ones, accL, 0, 0, 0);
    }

    // epilogue: C/D 32x32 layout: col = l31, row = (r&3) + 8*(r>>2) + 4*g
#pragma unroll
    for (int r = 0; r < 16; ++r) {
        int row = (r & 3) + 8 * (r >> 2) + 4 * g;
        int i = iw + row;
        float l = accL[r];
        int mi = mask[b * 1024 + i];
        float inv = (mi && l > 0.f) ? 1.0f / l : 0.f;
        size_t o = ((size_t)(b * 1024 + i)) * 256 + hh * 64;
        out[o + l31] = acc0[r] * inv;
        out[o + 32 + l31] = acc1[r] * inv;
    }
}

extern "C" void kernel_launch(void* const* d_in, const int* in_sizes, int n_in,
                              void* d_out, int out_size, void* d_ws, size_t ws_size,
                              hipStream_t stream) {
    const float* h = (const float*)d_in[0];
    const int* mask = (const int*)d_in[1];
    const float* W = (const float*)d_in[2];
    const float* a = (const float*)d_in[3];
    float* out = (float*)d_out;

    // ws: WhF bf16 frags [64 b4h][64 jt16][2 nt][64 lane][8] = 8 MiB; then E1F1, E2F2
    unsigned short* WhF = (unsigned short*)d_ws;
    float2* E1F1 = (float2*)((char*)d_ws + (size_t)64 * 64 * 2 * 64 * 8 * 2);
    float2* E2F2 = E1F1 + 64 * 1024;

    hipLaunchKernelGGL(k_wh, dim3(1024), dim3(256), 0, stream, h, mask, W, a, WhF, E1F1, E2F2);
    hipLaunchKernelGGL(k_attn, dim3(512), dim3(256), 0, stream, mask, WhF, E1F1, E2F2, out);
}

// Round 4
// 103.203 us; speedup vs baseline: 1.1325x; 1.0811x over previous
//
#include <hip/hip_runtime.h>

typedef short short8 __attribute__((ext_vector_type(8)));
typedef float floatx4 __attribute__((ext_vector_type(4)));
typedef float floatx16 __attribute__((ext_vector_type(16)));
typedef unsigned int u32;

#define NEG_SLOPE 0.2f

// pack {bf16_rtne(b), bf16_rtne(a)} into one u32 (a in low half)
__device__ __forceinline__ u32 pk_rtne(float a, float b) {
    u32 ua = __float_as_uint(a); ua += 0x7fffu + ((ua >> 16) & 1u);
    u32 ub = __float_as_uint(b); ub += 0x7fffu + ((ub >> 16) & 1u);
    return __builtin_amdgcn_perm(ub, ua, 0x07060302);
}
// pack {trunc16(b), trunc16(a)} — 1 inst per pair
__device__ __forceinline__ u32 pk_trunc(float a, float b) {
    return __builtin_amdgcn_perm(__float_as_uint(b), __float_as_uint(a), 0x07060302);
}
__device__ __forceinline__ void gl_lds16(const void* g, void* l) {
    __builtin_amdgcn_global_load_lds((__attribute__((address_space(1))) u32*)(void*)g,
                                     (__attribute__((address_space(3))) u32*)l, 16, 0, 0);
}

// ---------------------------------------------------------------------------
// Kernel 1: Wh = h @ W^T (single-pass bf16 MFMA, 16x16x32), barrier-free main
// loop. Scores s1/s2 computed EXACTLY in fp32 via s = h · (W^T a)  (v-GEMV
// folded into the W staging pass). Outputs:
//  - WhF: Wh^T as pre-swizzled 32x32x16 MFMA *B*-fragments
//    [b4h][jt16(64)][nt32(2)][lane(64)][8 bf16]
//    with k-slot permutation pi(g,jj) = (jj&3) + 4*g + 8*(jj>>2)
//  - E1F1[b4h,i] = (exp(s1), exp(0.2*s1)); E2F2[b4h,j] = m_j*(exp(s2), exp(0.2*s2))
// Grid 1024 = 256 mtiles x 4 heads; h-tile sharers stride 256 -> same XCD.
// (Unchanged since R0 — known-good.)
// ---------------------------------------------------------------------------
__global__ __launch_bounds__(256, 4) void k_wh(
    const float* __restrict__ hin, const int* __restrict__ mask,
    const float* __restrict__ W, const float* __restrict__ a,
    unsigned short* __restrict__ WhF, float2* __restrict__ E1F1,
    float2* __restrict__ E2F2)
{
    __shared__ unsigned short sBF[8 * 4 * 64 * 8];  // W as 16x16x32 B-frags, 32 KB
    __shared__ float sV1[256], sV2[256];

    const int t = threadIdx.x;
    const int bi = blockIdx.x;
    const int mtile = bi & 255, hh = bi >> 8;
    const int m0g = mtile * 64;             // global row = b*1024 + i0
    const int b = m0g >> 10, i0 = m0g & 1023;
    const int b4h = b * 4 + hh;
    const int wid = t >> 6, lane = t & 63;
    const int l15 = lane & 15, q = lane >> 4;

    sV1[t] = 0.f;
    sV2[t] = 0.f;
    __syncthreads();

    // ---- stage W (this head) as B-frags + v1/v2 partial GEMV ----
    float vp1[8] = {0, 0, 0, 0, 0, 0, 0, 0};
    float vp2[8] = {0, 0, 0, 0, 0, 0, 0, 0};
    {
        const int c = t & 31;               // k-chunk of 8 floats
        const int rb = t >> 5;
#pragma unroll
        for (int i = 0; i < 8; ++i) {
            int row = i * 8 + rb;           // d within head
            const float* gp = &W[((size_t)(hh * 64 + row)) * 256 + c * 8];
            float4 w0 = *(const float4*)gp;
            float4 w1 = *(const float4*)(gp + 4);
            float a1r = a[row], a2r = a[64 + row];
            vp1[0] += a1r * w0.x; vp1[1] += a1r * w0.y; vp1[2] += a1r * w0.z; vp1[3] += a1r * w0.w;
            vp1[4] += a1r * w1.x; vp1[5] += a1r * w1.y; vp1[6] += a1r * w1.z; vp1[7] += a1r * w1.w;
            vp2[0] += a2r * w0.x; vp2[1] += a2r * w0.y; vp2[2] += a2r * w0.z; vp2[3] += a2r * w0.w;
            vp2[4] += a2r * w1.x; vp2[5] += a2r * w1.y; vp2[6] += a2r * w1.z; vp2[7] += a2r * w1.w;
            uint4 pv;
            pv.x = pk_rtne(w0.x, w0.y); pv.y = pk_rtne(w0.z, w0.w);
            pv.z = pk_rtne(w1.x, w1.y); pv.w = pk_rtne(w1.z, w1.w);
            int kt = c >> 2, qq = c & 3, nt = row >> 4, r15 = row & 15;
            int idx16 = (kt * 4 + nt) * 64 + qq * 16 + r15;
            *(uint4*)&sBF[(idx16 ^ kt) * 8] = pv;   // XOR swizzle: 32-way -> 4-way
        }
    }
#pragma unroll
    for (int j = 0; j < 8; ++j) {
        vp1[j] += __shfl_xor(vp1[j], 32, 64);
        vp2[j] += __shfl_xor(vp2[j], 32, 64);
    }
    if (lane < 32) {
        const int c = t & 31;
#pragma unroll
        for (int j = 0; j < 8; ++j) {
            atomicAdd(&sV1[c * 8 + j], vp1[j]);
            atomicAdd(&sV2[c * 8 + j], vp2[j]);
        }
    }
    __syncthreads();

    // ---- main loop: A-frags direct from global, no barriers ----
    floatx4 acc[4];
#pragma unroll
    for (int nt = 0; nt < 4; ++nt) {
        floatx4 z = {0.f, 0.f, 0.f, 0.f};
        acc[nt] = z;
    }
    float s1a = 0.f, s2a = 0.f;
    const float* hrow = &hin[((size_t)(m0g + wid * 16 + l15)) * 256 + q * 8];
#pragma unroll
    for (int kt = 0; kt < 8; ++kt) {
        float4 h0 = *(const float4*)(hrow + kt * 32);
        float4 h1 = *(const float4*)(hrow + kt * 32 + 4);
        float4 v1a = *(const float4*)&sV1[kt * 32 + q * 8];
        float4 v1b = *(const float4*)&sV1[kt * 32 + q * 8 + 4];
        float4 v2a = *(const float4*)&sV2[kt * 32 + q * 8];
        float4 v2b = *(const float4*)&sV2[kt * 32 + q * 8 + 4];
        s1a += h0.x * v1a.x + h0.y * v1a.y + h0.z * v1a.z + h0.w * v1a.w
             + h1.x * v1b.x + h1.y * v1b.y + h1.z * v1b.z + h1.w * v1b.w;
        s2a += h0.x * v2a.x + h0.y * v2a.y + h0.z * v2a.z + h0.w * v2a.w
             + h1.x * v2b.x + h1.y * v2b.y + h1.z * v2b.z + h1.w * v2b.w;
        union { short8 s; uint4 u; } af;
        af.u.x = pk_rtne(h0.x, h0.y); af.u.y = pk_rtne(h0.z, h0.w);
        af.u.z = pk_rtne(h1.x, h1.y); af.u.w = pk_rtne(h1.z, h1.w);
#pragma unroll
        for (int nt = 0; nt < 4; ++nt) {
            int idx16 = (kt * 4 + nt) * 64 + lane;
            short8 bf = *(const short8*)&sBF[(idx16 ^ kt) * 8];
            acc[nt] = __builtin_amdgcn_mfma_f32_16x16x32_bf16(af.s, bf, acc[nt], 0, 0, 0);
        }
    }

    // ---- epilogue: store WhF as 32x32x16 B-frags under pi ----
    const int jt16 = (i0 >> 4) + wid;       // 16-j tile index within head
    const int g = q & 1, jb = (q >> 1) * 4;
#pragma unroll
    for (int nt = 0; nt < 4; ++nt) {
        int nt32 = nt >> 1;
        int l31 = (nt & 1) * 16 + l15;
        uint2 pv;
        pv.x = pk_rtne(acc[nt][0], acc[nt][1]);
        pv.y = pk_rtne(acc[nt][2], acc[nt][3]);
        size_t idx = ((((size_t)b4h * 64 + jt16) * 2 + nt32) * 64 + (g * 32 + l31)) * 8 + jb;
        *(uint2*)&WhF[idx] = pv;
    }

    // ---- scores: fold q (xor 16,32), write E/F ----
    s1a += __shfl_xor(s1a, 16, 64); s1a += __shfl_xor(s1a, 32, 64);
    s2a += __shfl_xor(s2a, 16, 64); s2a += __shfl_xor(s2a, 32, 64);
    if (lane < 16) {
        int i = i0 + wid * 16 + lane;
        E1F1[(size_t)b4h * 1024 + i] = make_float2(__expf(s1a), __expf(NEG_SLOPE * s1a));
        int mj = mask[b * 1024 + i];
        E2F2[(size_t)b4h * 1024 + i] =
            make_float2(mj ? __expf(s2a) : 0.f, mj ? __expf(NEG_SLOPE * s2a) : 0.f);
    }
}

// ---------------------------------------------------------------------------
// Kernel 2: out[i,:] = (sum_j w_ij Wh[j,:]) / (sum_j w_ij),
// w_ij = max(E1_i*E2_j, F1_i*F2_j).
//
// R3 structure (TLP lever): 1024 blocks x 256 thr, block = 64 rows; wave
// (rg,jh) = (row-group, j-half) -> each wave MFMAs 32 of 64 chunks. 16
// waves/CU (4 blocks x 4 waves; was 8) to hide LDS/L2/MFMA latency chains —
// the hypothesis for why R0-R2 all sit ~5x above their pipe floors at 2
// waves/SIMD. Wh B-frags stream from L2 (slab L2-resident; all 16 sharer
// blocks on one XCD) with 2-deep register prefetch; E/F staged once in LDS;
// zero in-loop barriers. jh-partials pair-reduced through padded LDS.
// fp32 pairwise (32+32) reassociation: numerator & denominator identical.
// ---------------------------------------------------------------------------
__global__ __launch_bounds__(256, 4) void k_attn(
    const int* __restrict__ mask,
    const unsigned short* __restrict__ WhF,
    const float2* __restrict__ E1F1, const float2* __restrict__ E2F2,
    float* __restrict__ out)
{
    __shared__ float2 sEF[1024];             // 8 KB, staged once
    __shared__ float sRed[2][64][49];        // 24.5 KB, pad 48->49: conflict-free

    const int t = threadIdx.x;
    const int bi = blockIdx.x;
    const int b4h = bi & 63, ib = bi >> 6;   // ib 0..15 -> 64-row slice
    const int b = b4h >> 2, hh = b4h & 3;
    const int i0 = ib * 64;
    const int wid = t >> 6, lane = t & 63;
    const int l31 = lane & 31, g = lane >> 5;
    const int rg = wid & 1, jh = wid >> 1;   // row-group, j-half
    const int iw = i0 + rg * 32;

    // stage the whole E2F2 slab (8 KB) once
    {
        const char* src = (const char*)(E2F2 + (size_t)b4h * 1024);
        gl_lds16(src + t * 16, (char*)sEF + t * 16);
        gl_lds16(src + 4096 + t * 16, (char*)sEF + 4096 + t * 16);
    }

    float2 e1 = E1F1[(size_t)b4h * 1024 + iw + l31];   // A-operand row m = l31
    const float E1 = e1.x, F1 = e1.y;

    floatx16 acc0, acc1, accL;
#pragma unroll
    for (int r = 0; r < 16; ++r) { acc0[r] = 0.f; acc1[r] = 0.f; accL[r] = 0.f; }
    const short ob = (short)0x3F80;          // bf16 1.0
    const short8 ones = {ob, ob, ob, ob, ob, ob, ob, ob};

    // per-lane base into the B-fragment slab: chunk c at + c*2048 (+1024 nt=1)
    const char* gbase = (const char*)WhF + (size_t)b4h * 131072 + (size_t)lane * 16;
    const int cb = jh * 32;                  // this wave's chunk window [cb, cb+32)

    // prime 2-deep Wh prefetch (issued before barrier: overlaps sEF staging)
    short8 ga0 = *(const short8*)(gbase + (size_t)cb * 2048);
    short8 ga1 = *(const short8*)(gbase + (size_t)cb * 2048 + 1024);
    short8 gb0 = *(const short8*)(gbase + (size_t)(cb + 1) * 2048);
    short8 gb1 = *(const short8*)(gbase + (size_t)(cb + 1) * 2048 + 1024);

    __syncthreads();                         // sEF ready (drains vmcnt incl. ga/gb)

    // prime E/F (chunk cb)
    float4 nA0, nA1, nB0, nB1;
    {
        const float4* pA = (const float4*)&sEF[cb * 16 + g * 4];
        const float4* pB = (const float4*)&sEF[cb * 16 + 8 + g * 4];
        nA0 = pA[0]; nA1 = pA[1]; nB0 = pB[0]; nB1 = pB[1];
    }

#pragma unroll 4
    for (int cr = 0; cr < 32; cr += 2) {
        // ---- sub-iter A: chunk cb+cr (frags in ga) ----
        {
            const float4 eA0 = nA0, eA1 = nA1, eB0 = nB0, eB1 = nB1;
            const int cn = cb + ((cr + 1) & 31);
            const float4* pA = (const float4*)&sEF[cn * 16 + g * 4];
            const float4* pB = (const float4*)&sEF[cn * 16 + 8 + g * 4];
            nA0 = pA[0]; nA1 = pA[1]; nB0 = pB[0]; nB1 = pB[1];
            const short8 bf0 = ga0, bf1 = ga1;
            const int cg = cb + ((cr + 2) & 31);
            ga0 = *(const short8*)(gbase + (size_t)cg * 2048);
            ga1 = *(const short8*)(gbase + (size_t)cg * 2048 + 1024);
            float w0 = fmaxf(E1 * eA0.x, F1 * eA0.y);
            float w1 = fmaxf(E1 * eA0.z, F1 * eA0.w);
            float w2 = fmaxf(E1 * eA1.x, F1 * eA1.y);
            float w3 = fmaxf(E1 * eA1.z, F1 * eA1.w);
            float w4 = fmaxf(E1 * eB0.x, F1 * eB0.y);
            float w5 = fmaxf(E1 * eB0.z, F1 * eB0.w);
            float w6 = fmaxf(E1 * eB1.x, F1 * eB1.y);
            float w7 = fmaxf(E1 * eB1.z, F1 * eB1.w);
            union { short8 s; u32 u[4]; } af;
            af.u[0] = pk_trunc(w0, w1);
            af.u[1] = pk_trunc(w2, w3);
            af.u[2] = pk_trunc(w4, w5);
            af.u[3] = pk_trunc(w6, w7);
            acc0 = __builtin_amdgcn_mfma_f32_32x32x16_bf16(af.s, bf0, acc0, 0, 0, 0);
            acc1 = __builtin_amdgcn_mfma_f32_32x32x16_bf16(af.s, bf1, acc1, 0, 0, 0);
            accL = __builtin_amdgcn_mfma_f32_32x32x16_bf16(af.s, ones, accL, 0, 0, 0);
        }
        // ---- sub-iter B: chunk cb+cr+1 (frags in gb) ----
        {
            const float4 eA0 = nA0, eA1 = nA1, eB0 = nB0, eB1 = nB1;
            const int cn = cb + ((cr + 2) & 31);
            const float4* pA = (const float4*)&sEF[cn * 16 + g * 4];
            const float4* pB = (const float4*)&sEF[cn * 16 + 8 + g * 4];
            nA0 = pA[0]; nA1 = pA[1]; nB0 = pB[0]; nB1 = pB[1];
            const short8 bf0 = gb0, bf1 = gb1;
            const int cg = cb + ((cr + 3) & 31);
            gb0 = *(const short8*)(gbase + (size_t)cg * 2048);
            gb1 = *(const short8*)(gbase + (size_t)cg * 2048 + 1024);
            float w0 = fmaxf(E1 * eA0.x, F1 * eA0.y);
            float w1 = fmaxf(E1 * eA0.z, F1 * eA0.w);
            float w2 = fmaxf(E1 * eA1.x, F1 * eA1.y);
            float w3 = fmaxf(E1 * eA1.z, F1 * eA1.w);
            float w4 = fmaxf(E1 * eB0.x, F1 * eB0.y);
            float w5 = fmaxf(E1 * eB0.z, F1 * eB0.w);
            float w6 = fmaxf(E1 * eB1.x, F1 * eB1.y);
            float w7 = fmaxf(E1 * eB1.z, F1 * eB1.w);
            union { short8 s; u32 u[4]; } af;
            af.u[0] = pk_trunc(w0, w1);
            af.u[1] = pk_trunc(w2, w3);
            af.u[2] = pk_trunc(w4, w5);
            af.u[3] = pk_trunc(w6, w7);
            acc0 = __builtin_amdgcn_mfma_f32_32x32x16_bf16(af.s, bf0, acc0, 0, 0, 0);
            acc1 = __builtin_amdgcn_mfma_f32_32x32x16_bf16(af.s, bf1, acc1, 0, 0, 0);
            accL = __builtin_amdgcn_mfma_f32_32x32x16_bf16(af.s, ones, accL, 0, 0, 0);
        }
    }

    // ---- pair-reduce jh partials through LDS ----
    if (jh == 1) {
        float* d = &sRed[rg][lane][0];
#pragma unroll
        for (int r = 0; r < 16; ++r) {
            d[r] = acc0[r]; d[16 + r] = acc1[r]; d[32 + r] = accL[r];
        }
    }
    __syncthreads();
    if (jh == 0) {
        const float* d = &sRed[rg][lane][0];
#pragma unroll
        for (int r = 0; r < 16; ++r) {
            acc0[r] += d[r]; acc1[r] += d[16 + r]; accL[r] += d[32 + r];
        }
        // epilogue: C/D 32x32 layout: col = l31, row = (r&3) + 8*(r>>2) + 4*g
#pragma unroll
        for (int r = 0; r < 16; ++r) {
            int row = (r & 3) + 8 * (r >> 2) + 4 * g;
            int i = iw + row;
            float l = accL[r];
            int mi = mask[b * 1024 + i];
            float inv = (mi && l > 0.f) ? 1.0f / l : 0.f;
            size_t o = ((size_t)(b * 1024 + i)) * 256 + hh * 64;
            out[o + l31] = acc0[r] * inv;
            out[o + 32 + l31] = acc1[r] * inv;
        }
    }
}

extern "C" void kernel_launch(void* const* d_in, const int* in_sizes, int n_in,
                              void* d_out, int out_size, void* d_ws, size_t ws_size,
                              hipStream_t stream) {
    const float* h = (const float*)d_in[0];
    const int* mask = (const int*)d_in[1];
    const float* W = (const float*)d_in[2];
    const float* a = (const float*)d_in[3];
    float* out = (float*)d_out;

    // ws: WhF bf16 frags [64 b4h][64 jt16][2 nt][64 lane][8] = 8 MiB; then E1F1, E2F2
    unsigned short* WhF = (unsigned short*)d_ws;
    float2* E1F1 = (float2*)((char*)d_ws + (size_t)64 * 64 * 2 * 64 * 8 * 2);
    float2* E2F2 = E1F1 + 64 * 1024;

    hipLaunchKernelGGL(k_wh, dim3(1024), dim3(256), 0, stream, h, mask, W, a, WhF, E1F1, E2F2);
    hipLaunchKernelGGL(k_attn, dim3(1024), dim3(256), 0, stream, mask, WhF, E1F1, E2F2, out);
}